// Round 5
// baseline (108.125 us; speedup 1.0000x reference)
//
#include <hip/hip_runtime.h>
#include <hip/hip_bf16.h>

// Problem constants (fixed by the reference):
constexpr int NB = 256;   // batch
constexpr int SQ = 512;   // sequence length
constexpr int ED = 512;   // encoder dim
constexpr int DD = 512;   // decoder dim
constexpr int UU = 64;    // attention units
constexpr int NT = 4;     // s-tiles per batch
constexpr int TS = 128;   // rows per tile

typedef __attribute__((ext_vector_type(8))) short bf16x8;
typedef __attribute__((ext_vector_type(4))) float f32x4;
typedef __attribute__((ext_vector_type(4))) unsigned int u32x4;

__device__ __forceinline__ unsigned short bf16_rne(float f) {
  unsigned int u = __float_as_uint(f);
  u += 0x7FFFu + ((u >> 16) & 1u);
  return (unsigned short)(u >> 16);
}

// Truncate-truncate pair split: v ~= hi + lo exactly to ~2^-16 rel.
// Packs two elements into one dword (elem i in low half, i+1 in high half).
__device__ __forceinline__ uint2 split2(float v0, float v1) {
  unsigned int u0 = __float_as_uint(v0), u1 = __float_as_uint(v1);
  unsigned int h0 = u0 & 0xFFFF0000u, h1 = u1 & 0xFFFF0000u;
  unsigned int hi = (u0 >> 16) | h1;
  float r0 = v0 - __uint_as_float(h0);
  float r1 = v1 - __uint_as_float(h1);
  unsigned int lo = (__float_as_uint(r0) >> 16) | (__float_as_uint(r1) & 0xFFFF0000u);
  return make_uint2(hi, lo);
}

// ws layout (bytes):
//   [0,       131072) : w2 hi/lo bf16 fragments
//   [131072,  196608) : dec[256][64]  (w1 proj + both biases folded)
//   [196608,  200704) : mbuf[256][4]  tile max
//   [200704,  204800) : lbuf[256][4]  tile exp-sum
//   [204800, 2301952) : ctile[256][4][512] partial contexts
constexpr size_t WS_DEC   = 131072;
constexpr size_t WS_MBUF  = 196608;
constexpr size_t WS_LBUF  = 200704;
constexpr size_t WS_CTILE = 204800;

// ---------------------------------------------------------------------------
// Kernel P1: split w2 (512x64 fp32) into hi/lo bf16, pre-arranged in MFMA
// B-fragment order for mfma_f32_16x16x32_bf16 (B[k][col]: lane l holds
// k=(l>>4)*8+j, col=l&15). Per k-step an 8192-byte contiguous block.
// ---------------------------------------------------------------------------
__global__ void prep_w2_frags(const float* __restrict__ w2,
                              unsigned short* __restrict__ wsb) {
  int tid = blockIdx.x * 256 + threadIdx.x;   // 0..65535
  int j    = tid & 7;
  int lane = (tid >> 3) & 63;
  int nt   = (tid >> 9) & 3;
  int hl   = (tid >> 11) & 1;
  int ks   = tid >> 12;
  int e = ks * 32 + (lane >> 4) * 8 + j;
  int u = nt * 16 + (lane & 15);
  float v = w2[e * UU + u];
  unsigned short hi = bf16_rne(v);
  unsigned short o;
  if (hl == 0) {
    o = hi;
  } else {
    float hif = __uint_as_float((unsigned int)hi << 16);
    o = bf16_rne(v - hif);   // residual, next ~8 mantissa bits
  }
  wsb[tid] = o;
}

// ---------------------------------------------------------------------------
// Kernel P2: dec[b,u] = sum_e dh[b,e]*w1[e,u] + w1b[u] + w2b[u]
// ---------------------------------------------------------------------------
__global__ __launch_bounds__(256) void dec_proj(
    const float* __restrict__ dh, const float* __restrict__ w1,
    const float* __restrict__ w1b, const float* __restrict__ w2b,
    float* __restrict__ dec_ws) {
  const int b = blockIdx.x;
  const int t = threadIdx.x;
  const int wave = t >> 6;
  const int lane = t & 63;
  __shared__ float red[256];
  const float* dhb = dh + (size_t)b * DD;
  const int e0 = wave * 128;
  float s = 0.f;
  #pragma unroll 8
  for (int i = 0; i < 128; ++i) {
    int e = e0 + i;
    s = fmaf(dhb[e], w1[e * UU + lane], s);   // dh broadcast, w1 coalesced
  }
  red[t] = s;
  __syncthreads();
  if (t < 64) {
    float d = w1b[t] + w2b[t] + red[t] + red[64 + t] + red[128 + t] + red[192 + t];
    dec_ws[b * UU + t] = d;
  }
}

// ---------------------------------------------------------------------------
// Kernel A: per (b, s-tile of 128 rows). 256 threads = 4 waves; wave w owns
// rows [tile*128 + w*32, +32). BARRIER-FREE k-loop: B fragments are loaded
// straight from global (L2-broadcast across the 1024 blocks) instead of LDS
// double-buffering — round-3's 16 per-k barriers each drained vmcnt(0) and
// exposed full HBM latency serially. Single barrier after the k-loop.
// ---------------------------------------------------------------------------
__global__ __launch_bounds__(256, 4) void attn_tile(
    const float* __restrict__ x,     // [256,512,512]
    const float* __restrict__ vk,    // [64]
    const unsigned short* __restrict__ wsb,
    const float* __restrict__ dec_ws,
    float* __restrict__ mbuf, float* __restrict__ lbuf,
    float* __restrict__ ctile,
    float* __restrict__ out)
{
  const int b    = blockIdx.x >> 2;
  const int tile = blockIdx.x & 3;
  const int t = threadIdx.x;
  const int wave = t >> 6;
  const int lane = t & 63;

  __shared__ float dec_lds[64];
  __shared__ float v_lds[64];
  __shared__ float score_lds[TS];
  __shared__ float p_lds[TS];
  __shared__ __align__(16) float cpart[2 * 512];

  if (t < 64) {
    dec_lds[t] = dec_ws[b * UU + t];
    v_lds[t] = vk[t];
  }

  // ---- projection GEMM over this tile's 128 rows (no barriers) ------------
  const int row0 = tile * TS + wave * 32;
  const float* aptr =
      x + ((size_t)b * SQ + row0 + (lane & 15)) * ED + ((lane >> 4) * 8);
  const unsigned short* bptr = wsb + lane * 8;

  const f32x4 zero4 = {0.f, 0.f, 0.f, 0.f};
  f32x4 acc[2][4];
  #pragma unroll
  for (int m = 0; m < 2; ++m)
    #pragma unroll
    for (int n = 0; n < 4; ++n) acc[m][n] = zero4;

  #pragma unroll 4
  for (int k = 0; k < 16; ++k) {
    // B fragments: global loads, same address across blocks -> L2 broadcast
    bf16x8 bhi[4], blo[4];
    #pragma unroll
    for (int n = 0; n < 4; ++n) {
      bhi[n] = *(const bf16x8*)(bptr + k * 4096 + n * 512);
      blo[n] = *(const bf16x8*)(bptr + k * 4096 + 2048 + n * 512);
    }
    #pragma unroll
    for (int m = 0; m < 2; ++m) {
      float4 a0 = *(const float4*)(aptr + (size_t)(m * 16) * ED + k * 32);
      float4 a1 = *(const float4*)(aptr + (size_t)(m * 16) * ED + k * 32 + 4);
      uint2 p0 = split2(a0.x, a0.y);
      uint2 p1 = split2(a0.z, a0.w);
      uint2 p2 = split2(a1.x, a1.y);
      uint2 p3 = split2(a1.z, a1.w);
      u32x4 hi, lo;
      hi[0] = p0.x; lo[0] = p0.y;
      hi[1] = p1.x; lo[1] = p1.y;
      hi[2] = p2.x; lo[2] = p2.y;
      hi[3] = p3.x; lo[3] = p3.y;
      bf16x8 ahi = __builtin_bit_cast(bf16x8, hi);
      bf16x8 alo = __builtin_bit_cast(bf16x8, lo);
      #pragma unroll
      for (int n = 0; n < 4; ++n) {
        acc[m][n] = __builtin_amdgcn_mfma_f32_16x16x32_bf16(ahi, bhi[n], acc[m][n], 0, 0, 0);
        acc[m][n] = __builtin_amdgcn_mfma_f32_16x16x32_bf16(ahi, blo[n], acc[m][n], 0, 0, 0);
        acc[m][n] = __builtin_amdgcn_mfma_f32_16x16x32_bf16(alo, bhi[n], acc[m][n], 0, 0, 0);
      }
    }
  }
  __syncthreads();   // dec_lds/v_lds visible; score_lds safe to write

  // ---- scores: score[s] = sum_u tanh(enc + dec) * v ------------------------
  // C/D layout (m89/m91): col u = lane&15 (+16*n), row = (lane>>4)*4 + r
  {
    const int ul = lane & 15;
    const int rg = lane >> 4;
    #pragma unroll
    for (int m = 0; m < 2; ++m) {
      #pragma unroll
      for (int r = 0; r < 4; ++r) {
        float part = 0.f;
        #pragma unroll
        for (int n = 0; n < 4; ++n) {
          int u = n * 16 + ul;
          float z = acc[m][n][r] + dec_lds[u];
          float ez = __expf(2.f * z);              // tanh via exp
          float th = 1.f - 2.f / (ez + 1.f);
          part = fmaf(th, v_lds[u], part);
        }
        part += __shfl_xor(part, 1);
        part += __shfl_xor(part, 2);
        part += __shfl_xor(part, 4);
        part += __shfl_xor(part, 8);
        if (ul == 0) score_lds[wave * 32 + m * 16 + rg * 4 + r] = part;
      }
    }
  }
  __syncthreads();

  // ---- tile-local softmax pieces ------------------------------------------
  float mx = -1e30f;
  #pragma unroll
  for (int i = 0; i < TS; i += 4) {
    float4 s4 = *(const float4*)&score_lds[i];
    mx = fmaxf(mx, fmaxf(fmaxf(s4.x, s4.y), fmaxf(s4.z, s4.w)));
  }
  if (t < TS) {
    float p = __expf(score_lds[t] - mx);
    p_lds[t] = p;
    // unnormalized p into the att output region; combine() rescales in place
    out[(size_t)NB * ED + (size_t)b * SQ + tile * TS + t] = p;
  }
  __syncthreads();
  if (t < 64) {
    float v = p_lds[t] + p_lds[t + 64];
    v += __shfl_xor(v, 1);  v += __shfl_xor(v, 2);
    v += __shfl_xor(v, 4);  v += __shfl_xor(v, 8);
    v += __shfl_xor(v, 16); v += __shfl_xor(v, 32);
    if (t == 0) {
      mbuf[b * NT + tile] = mx;
      lbuf[b * NT + tile] = v;
    }
  }

  // ---- partial context: ctile[e] = sum_{s in tile} p[s] x[b,s,e] ----------
  {
    const int subset = t >> 7;          // 0..1
    const int ec = t & 127;             // float4 e-chunk
    const float* xc = x + ((size_t)b * SQ + tile * TS) * ED + ec * 4;
    f32x4 c = zero4;
    #pragma unroll 8
    for (int i = 0; i < 64; ++i) {
      int s = subset + i * 2;
      float4 v = *(const float4*)(xc + (size_t)s * ED);
      float p = p_lds[s];
      c[0] = fmaf(p, v.x, c[0]);
      c[1] = fmaf(p, v.y, c[1]);
      c[2] = fmaf(p, v.z, c[2]);
      c[3] = fmaf(p, v.w, c[3]);
    }
    *(f32x4*)&cpart[subset * 512 + ec * 4] = c;
  }
  __syncthreads();
  #pragma unroll
  for (int e = t; e < 512; e += 256) {
    ctile[((size_t)b * NT + tile) * ED + e] = cpart[e] + cpart[512 + e];
  }
}

// ---------------------------------------------------------------------------
// Kernel B: combine tiles. M = max m_t; L = sum l_t e^{m_t-M};
// att *= e^{m_tile-M}/L (in place); ctx = sum_t ctile_t e^{m_t-M}/L.
// ---------------------------------------------------------------------------
__global__ __launch_bounds__(256) void combine(
    const float* __restrict__ mbuf, const float* __restrict__ lbuf,
    const float* __restrict__ ctile, float* __restrict__ out) {
  const int b = blockIdx.x;
  const int t = threadIdx.x;
  float m0 = mbuf[b * NT + 0], m1 = mbuf[b * NT + 1];
  float m2 = mbuf[b * NT + 2], m3 = mbuf[b * NT + 3];
  float M = fmaxf(fmaxf(m0, m1), fmaxf(m2, m3));
  float e0 = __expf(m0 - M), e1 = __expf(m1 - M);
  float e2 = __expf(m2 - M), e3 = __expf(m3 - M);
  float L = lbuf[b * NT + 0] * e0 + lbuf[b * NT + 1] * e1 +
            lbuf[b * NT + 2] * e2 + lbuf[b * NT + 3] * e3;
  float inv = 1.f / L;
  float sc[NT] = {e0 * inv, e1 * inv, e2 * inv, e3 * inv};

  float* att = out + (size_t)NB * ED + (size_t)b * SQ;
  #pragma unroll
  for (int s = t; s < SQ; s += 256) att[s] *= sc[s >> 7];

  const float* ct = ctile + (size_t)b * NT * ED;
  #pragma unroll
  for (int e = t; e < ED; e += 256) {
    float c = ct[e] * sc[0] + ct[ED + e] * sc[1] +
              ct[2 * ED + e] * sc[2] + ct[3 * ED + e] * sc[3];
    out[(size_t)b * ED + e] = c;
  }
}

// ---------------------------------------------------------------------------
extern "C" void kernel_launch(void* const* d_in, const int* in_sizes, int n_in,
                              void* d_out, int out_size, void* d_ws, size_t ws_size,
                              hipStream_t stream) {
  const float* dh  = (const float*)d_in[0];
  const float* x   = (const float*)d_in[1];
  const float* w1  = (const float*)d_in[2];
  const float* w1b = (const float*)d_in[3];
  const float* w2  = (const float*)d_in[4];
  const float* w2b = (const float*)d_in[5];
  const float* vk  = (const float*)d_in[6];
  // d_in[7] = v_bias: softmax exactly invariant -> unused.
  unsigned short* wsb = (unsigned short*)d_ws;
  float* dec_ws = (float*)((char*)d_ws + WS_DEC);
  float* mbuf   = (float*)((char*)d_ws + WS_MBUF);
  float* lbuf   = (float*)((char*)d_ws + WS_LBUF);
  float* ctile  = (float*)((char*)d_ws + WS_CTILE);
  float* out = (float*)d_out;

  prep_w2_frags<<<256, 256, 0, stream>>>(w2, wsb);
  dec_proj<<<NB, 256, 0, stream>>>(dh, w1, w1b, w2b, dec_ws);
  attn_tile<<<NB * NT, 256, 0, stream>>>(x, vk, wsb, dec_ws, mbuf, lbuf, ctile, out);
  combine<<<NB, 256, 0, stream>>>(mbuf, lbuf, ctile, out);
}

// Round 7
// 97.381 us; speedup vs baseline: 1.1103x; 1.1103x over previous
//
#include <hip/hip_runtime.h>
#include <hip/hip_bf16.h>

// Problem constants (fixed by the reference):
constexpr int NB = 256;   // batch
constexpr int SQ = 512;   // sequence length
constexpr int ED = 512;   // encoder dim
constexpr int DD = 512;   // decoder dim
constexpr int UU = 64;    // attention units
constexpr int NT = 4;     // s-tiles per batch
constexpr int TS = 128;   // rows per tile

typedef __attribute__((ext_vector_type(8))) short bf16x8;
typedef __attribute__((ext_vector_type(4))) float f32x4;
typedef __attribute__((ext_vector_type(4))) unsigned int u32x4;

#define MEMFENCE asm volatile("" ::: "memory")
#define SBAR do { MEMFENCE; __builtin_amdgcn_s_barrier(); MEMFENCE; } while (0)
#define WAITVM(n) asm volatile("s_waitcnt vmcnt(" #n ")" ::: "memory")

__device__ __forceinline__ void stage16(const void* g, void* l) {
  // async global->LDS DMA, 16B per lane; LDS dest = wave-uniform base + lane*16
  __builtin_amdgcn_global_load_lds(
      (const __attribute__((address_space(1))) void*)g,
      (__attribute__((address_space(3))) void*)l, 16, 0, 0);
}

__device__ __forceinline__ unsigned short bf16_rne(float f) {
  unsigned int u = __float_as_uint(f);
  u += 0x7FFFu + ((u >> 16) & 1u);
  return (unsigned short)(u >> 16);
}

// Truncate-truncate pair split: v ~= hi + lo to ~2^-16 rel.
__device__ __forceinline__ uint2 split2(float v0, float v1) {
  unsigned int u0 = __float_as_uint(v0), u1 = __float_as_uint(v1);
  unsigned int h0 = u0 & 0xFFFF0000u, h1 = u1 & 0xFFFF0000u;
  unsigned int hi = (u0 >> 16) | h1;
  float r0 = v0 - __uint_as_float(h0);
  float r1 = v1 - __uint_as_float(h1);
  unsigned int lo = (__float_as_uint(r0) >> 16) | (__float_as_uint(r1) & 0xFFFF0000u);
  return make_uint2(hi, lo);
}

// ws layout (bytes):
constexpr size_t WS_DEC   = 131072;
constexpr size_t WS_MBUF  = 196608;
constexpr size_t WS_LBUF  = 200704;
constexpr size_t WS_CTILE = 204800;

// ---------------------------------------------------------------------------
// Kernel P1: split w2 into hi/lo bf16 MFMA B-fragments; per k-step 8192 B.
// ---------------------------------------------------------------------------
__global__ void prep_w2_frags(const float* __restrict__ w2,
                              unsigned short* __restrict__ wsb) {
  int tid = blockIdx.x * 256 + threadIdx.x;   // 0..65535
  int j    = tid & 7;
  int lane = (tid >> 3) & 63;
  int nt   = (tid >> 9) & 3;
  int hl   = (tid >> 11) & 1;
  int ks   = tid >> 12;
  int e = ks * 32 + (lane >> 4) * 8 + j;
  int u = nt * 16 + (lane & 15);
  float v = w2[e * UU + u];
  unsigned short hi = bf16_rne(v);
  unsigned short o;
  if (hl == 0) {
    o = hi;
  } else {
    float hif = __uint_as_float((unsigned int)hi << 16);
    o = bf16_rne(v - hif);
  }
  wsb[tid] = o;
}

// ---------------------------------------------------------------------------
// Kernel P2: dec[b,u] = dh[b,:]·w1[:,u] + w1b[u] + w2b[u]
// ---------------------------------------------------------------------------
__global__ __launch_bounds__(256) void dec_proj(
    const float* __restrict__ dh, const float* __restrict__ w1,
    const float* __restrict__ w1b, const float* __restrict__ w2b,
    float* __restrict__ dec_ws) {
  const int b = blockIdx.x;
  const int t = threadIdx.x;
  const int wave = t >> 6;
  const int lane = t & 63;
  __shared__ float red[256];
  const float* dhb = dh + (size_t)b * DD;
  const int e0 = wave * 128;
  float s = 0.f;
  #pragma unroll 8
  for (int i = 0; i < 128; ++i) {
    int e = e0 + i;
    s = fmaf(dhb[e], w1[e * UU + lane], s);
  }
  red[t] = s;
  __syncthreads();
  if (t < 64) {
    float d = w1b[t] + w2b[t] + red[t] + red[64 + t] + red[128 + t] + red[192 + t];
    dec_ws[b * UU + t] = d;
  }
}

// ---------------------------------------------------------------------------
// Kernel A: per (b, 128-row tile), 512 threads = 8 waves (wave = 16 rows).
// Counted-vmcnt global_load_lds pipeline (3-slot ring, 2 chunks in flight =
// 48 KB/block; 2 blocks/CU => ~96 KB/CU in flight, vs the 9.2 KB needed to
// saturate the per-CU HBM share — rounds 1-5 had ~2 KB => 2.4 TB/s ceiling).
// A-chunks source-pre-swizzled (^((row&7)<<4)) so ds_read_b128 of 16 rows at
// stride 128 B is bank-conflict-free (LDS dest of global_load_lds is linear).
// ---------------------------------------------------------------------------
__global__ __launch_bounds__(512, 4) void attn_tile(
    const float* __restrict__ x,
    const float* __restrict__ vk,
    const unsigned short* __restrict__ wsb,
    const float* __restrict__ dec_ws,
    float* __restrict__ mbuf, float* __restrict__ lbuf,
    float* __restrict__ ctile,
    float* __restrict__ out)
{
  const int b    = blockIdx.x >> 2;
  const int tile = blockIdx.x & 3;
  const int t = threadIdx.x;
  const int wave = t >> 6;
  const int lane = t & 63;

  // ring: A slots 3x16384 @0, B slots 3x8192 @49152  (73728 B total)
  __shared__ __align__(16) unsigned char ring[73728];
  __shared__ float score_lds[TS];
  __shared__ float p_lds[TS];
  __shared__ float dec_lds[64];
  __shared__ float v_lds[64];
  __shared__ __align__(16) float part[2][512];

  if (t < 64) {
    dec_lds[t] = dec_ws[b * UU + t];   // wave-0 vmcnt events drain first; safe
    v_lds[t] = vk[t];
  }

  const char* xt = (const char*)x + (size_t)(b * SQ + tile * TS) * (ED * 4);
  const char* wsbb = (const char*)wsb;

  // --- staging helpers (3 vm-insts/wave per chunk: A=2, B=1) ---------------
  auto stageA = [&](int k, int slot) {
    #pragma unroll
    for (int s2 = 0; s2 < 2; ++s2) {
      int L = s2 * 8192 + t * 16;          // linear LDS byte in A slot
      int row = L >> 7, o = L & 127;
      stage16(xt + (size_t)row * 2048 + (size_t)(k * 128 + (o ^ ((row & 7) << 4))),
              &ring[slot * 16384 + L]);
    }
  };
  auto stageB = [&](int k, int slot) {
    stage16(wsbb + (size_t)k * 8192 + t * 16, &ring[49152 + slot * 8192 + t * 16]);
  };

  // --- projection GEMM: counted-vmcnt pipelined k-loop ---------------------
  const int j16 = lane >> 4;            // which 8-float group of the k-slab
  const int rlocal = lane & 15;
  const int row = wave * 16 + rlocal;
  const int sw = (lane & 7) << 4;       // row&7 == lane&7

  const f32x4 zero4 = {0.f, 0.f, 0.f, 0.f};
  f32x4 acc[4];
  #pragma unroll
  for (int n = 0; n < 4; ++n) acc[n] = zero4;

  stageA(0, 0); stageB(0, 0);           // prologue: chunks 0,1 in flight
  stageA(1, 1); stageB(1, 1);

  #pragma unroll
  for (int k = 0; k < 16; ++k) {
    if (k < 15) { WAITVM(3); } else { WAITVM(0); }  // chunk k landed (own wave)
    SBAR;                                            // => landed for all waves
    if (k < 14) { stageA(k + 2, (k + 2) % 3); stageB(k + 2, (k + 2) % 3); }

    const unsigned char* Ab = &ring[(k % 3) * 16384] + row * 128;
    const unsigned char* Bb = &ring[49152 + (k % 3) * 8192];
    f32x4 a0 = *(const f32x4*)(Ab + ((j16 * 32) ^ sw));
    f32x4 a1 = *(const f32x4*)(Ab + ((j16 * 32 + 16) ^ sw));
    bf16x8 bhi[4], blo[4];
    #pragma unroll
    for (int n = 0; n < 4; ++n) {
      bhi[n] = *(const bf16x8*)(Bb + n * 1024 + lane * 16);
      blo[n] = *(const bf16x8*)(Bb + 4096 + n * 1024 + lane * 16);
    }
    uint2 p0 = split2(a0[0], a0[1]);
    uint2 p1 = split2(a0[2], a0[3]);
    uint2 p2 = split2(a1[0], a1[1]);
    uint2 p3 = split2(a1[2], a1[3]);
    u32x4 hi, lo;
    hi[0] = p0.x; lo[0] = p0.y;
    hi[1] = p1.x; lo[1] = p1.y;
    hi[2] = p2.x; lo[2] = p2.y;
    hi[3] = p3.x; lo[3] = p3.y;
    bf16x8 ahi = __builtin_bit_cast(bf16x8, hi);
    bf16x8 alo = __builtin_bit_cast(bf16x8, lo);
    #pragma unroll
    for (int n = 0; n < 4; ++n) {
      acc[n] = __builtin_amdgcn_mfma_f32_16x16x32_bf16(ahi, bhi[n], acc[n], 0, 0, 0);
      acc[n] = __builtin_amdgcn_mfma_f32_16x16x32_bf16(ahi, blo[n], acc[n], 0, 0, 0);
      acc[n] = __builtin_amdgcn_mfma_f32_16x16x32_bf16(alo, bhi[n], acc[n], 0, 0, 0);
    }
  }

  // ---- scores: score[s] = sum_u tanh(enc + dec) * v ------------------------
  // C/D layout (m89/m91): col u = lane&15 (+16*n), row = (lane>>4)*4 + r
  {
    const int ul = lane & 15;
    const int rg = lane >> 4;
    #pragma unroll
    for (int r = 0; r < 4; ++r) {
      float partsc = 0.f;
      #pragma unroll
      for (int n = 0; n < 4; ++n) {
        int u = n * 16 + ul;
        float z = acc[n][r] + dec_lds[u];
        float ez = __expf(2.f * z);              // tanh via exp
        float th = 1.f - 2.f / (ez + 1.f);
        partsc = fmaf(th, v_lds[u], partsc);
      }
      partsc += __shfl_xor(partsc, 1);
      partsc += __shfl_xor(partsc, 2);
      partsc += __shfl_xor(partsc, 4);
      partsc += __shfl_xor(partsc, 8);
      if (ul == 0) score_lds[wave * 16 + rg * 4 + r] = partsc;
    }
  }
  __syncthreads();

  // ---- tile-local softmax pieces ------------------------------------------
  float mx = -1e30f;
  #pragma unroll
  for (int i = 0; i < TS; i += 4) {
    float4 s4 = *(const float4*)&score_lds[i];
    mx = fmaxf(mx, fmaxf(fmaxf(s4.x, s4.y), fmaxf(s4.z, s4.w)));
  }
  if (t < TS) {
    float p = __expf(score_lds[t] - mx);
    p_lds[t] = p;
    out[(size_t)NB * ED + (size_t)b * SQ + tile * TS + t] = p;  // unnormalized
  }
  __syncthreads();
  if (t < 64) {
    float v = p_lds[t] + p_lds[t + 64];
    v += __shfl_xor(v, 1);  v += __shfl_xor(v, 2);
    v += __shfl_xor(v, 4);  v += __shfl_xor(v, 8);
    v += __shfl_xor(v, 16); v += __shfl_xor(v, 32);
    if (t == 0) {
      mbuf[b * NT + tile] = mx;
      lbuf[b * NT + tile] = v;
    }
  }

  // ---- context: re-stream tile through the ring (L3-hot), counted vmcnt ---
  // chunk = 8 rows x 512 cols = 16 KB, linear; 2 insts/wave per chunk.
  auto stageC = [&](int c, int slot) {
    #pragma unroll
    for (int s2 = 0; s2 < 2; ++s2) {
      int L = s2 * 8192 + t * 16;
      stage16(xt + (size_t)(c * 8) * 2048 + L, &ring[slot * 16384 + L]);
    }
  };
  const int rsub = t >> 7;              // 0..3 -> rows {rsub, rsub+4} per chunk
  const int e16 = (t & 127) * 16;       // byte offset of this thread's f32x4
  f32x4 c4 = zero4;

  stageC(0, 0);
  stageC(1, 1);
  #pragma unroll
  for (int c = 0; c < 16; ++c) {
    if (c < 15) { WAITVM(2); } else { WAITVM(0); }
    SBAR;
    if (c < 14) stageC(c + 2, (c + 2) % 3);
    const unsigned char* base = &ring[(c % 3) * 16384];
    #pragma unroll
    for (int q = 0; q < 2; ++q) {
      int rl = rsub + 4 * q;
      f32x4 xv = *(const f32x4*)(base + rl * 2048 + e16);
      float pp = p_lds[c * 8 + rl];
      c4[0] = fmaf(pp, xv[0], c4[0]);
      c4[1] = fmaf(pp, xv[1], c4[1]);
      c4[2] = fmaf(pp, xv[2], c4[2]);
      c4[3] = fmaf(pp, xv[3], c4[3]);
    }
  }

  // two-pass partial reduce into part[2][512]
  if (rsub < 2) *(f32x4*)&part[rsub][(t & 127) * 4] = c4;
  __syncthreads();
  if (rsub >= 2) {
    f32x4 tmp = *(f32x4*)&part[rsub - 2][(t & 127) * 4];
    tmp[0] += c4[0]; tmp[1] += c4[1]; tmp[2] += c4[2]; tmp[3] += c4[3];
    *(f32x4*)&part[rsub - 2][(t & 127) * 4] = tmp;
  }
  __syncthreads();
  ctile[((size_t)b * NT + tile) * ED + t] = part[0][t] + part[1][t];
}

// ---------------------------------------------------------------------------
// Kernel B: combine tiles (flash algebra). att *= e^{m_t-M}/L; ctx = sum.
// ---------------------------------------------------------------------------
__global__ __launch_bounds__(256) void combine(
    const float* __restrict__ mbuf, const float* __restrict__ lbuf,
    const float* __restrict__ ctile, float* __restrict__ out) {
  const int b = blockIdx.x;
  const int t = threadIdx.x;
  float m0 = mbuf[b * NT + 0], m1 = mbuf[b * NT + 1];
  float m2 = mbuf[b * NT + 2], m3 = mbuf[b * NT + 3];
  float M = fmaxf(fmaxf(m0, m1), fmaxf(m2, m3));
  float e0 = __expf(m0 - M), e1 = __expf(m1 - M);
  float e2 = __expf(m2 - M), e3 = __expf(m3 - M);
  float L = lbuf[b * NT + 0] * e0 + lbuf[b * NT + 1] * e1 +
            lbuf[b * NT + 2] * e2 + lbuf[b * NT + 3] * e3;
  float inv = 1.f / L;
  float sc[NT] = {e0 * inv, e1 * inv, e2 * inv, e3 * inv};

  float* att = out + (size_t)NB * ED + (size_t)b * SQ;
  #pragma unroll
  for (int s = t; s < SQ; s += 256) att[s] *= sc[s >> 7];

  const float* ct = ctile + (size_t)b * NT * ED;
  #pragma unroll
  for (int e = t; e < ED; e += 256) {
    float c = ct[e] * sc[0] + ct[ED + e] * sc[1] +
              ct[2 * ED + e] * sc[2] + ct[3 * ED + e] * sc[3];
    out[(size_t)b * ED + e] = c;
  }
}

// ---------------------------------------------------------------------------
extern "C" void kernel_launch(void* const* d_in, const int* in_sizes, int n_in,
                              void* d_out, int out_size, void* d_ws, size_t ws_size,
                              hipStream_t stream) {
  const float* dh  = (const float*)d_in[0];
  const float* x   = (const float*)d_in[1];
  const float* w1  = (const float*)d_in[2];
  const float* w1b = (const float*)d_in[3];
  const float* w2  = (const float*)d_in[4];
  const float* w2b = (const float*)d_in[5];
  const float* vk  = (const float*)d_in[6];
  // d_in[7] = v_bias: softmax exactly invariant -> unused.
  unsigned short* wsb = (unsigned short*)d_ws;
  float* dec_ws = (float*)((char*)d_ws + WS_DEC);
  float* mbuf   = (float*)((char*)d_ws + WS_MBUF);
  float* lbuf   = (float*)((char*)d_ws + WS_LBUF);
  float* ctile  = (float*)((char*)d_ws + WS_CTILE);
  float* out = (float*)d_out;

  prep_w2_frags<<<256, 256, 0, stream>>>(w2, wsb);
  dec_proj<<<NB, 256, 0, stream>>>(dh, w1, w1b, w2b, dec_ws);
  attn_tile<<<NB * NT, 512, 0, stream>>>(x, vk, wsb, dec_ws, mbuf, lbuf, ctile, out);
  combine<<<NB, 256, 0, stream>>>(mbuf, lbuf, ctile, out);
}